// Round 18
// baseline (198.807 us; speedup 1.0000x reference)
//
#include <hip/hip_runtime.h>
#include <cstdint>
#include <cstddef>

typedef __bf16 bf16;
typedef __bf16 bf16x8 __attribute__((ext_vector_type(8)));
typedef __bf16 bf16x4 __attribute__((ext_vector_type(4)));
typedef float  f32x4  __attribute__((ext_vector_type(4)));

#define C_EPS 1e-5f
#define NC_ 64
#define NH_ 256
#define NW_ 256
#define HP_ (NH_*NW_)

// workspace layout (bytes)
#define OFF_W1   0ull
#define OFF_W2   73728ull
#define OFF_AFF  147456ull

// acc staging stride (phase 5): 536 B -> 134 ≡ 6 (mod 32) banks, <=2-way.
#define ACC_STRIDE 536

// swizzled LDS byte offset for [pixel p][granule g] bf16 tile (128 B/pixel),
// 16-B-granule XOR swizzle: pixel stride 128 B == 32 banks -> must swizzle.
// granule g holds ci 8g..8g+7 (staging stores ci4 at g=ci4>>1, +8B if odd).
__device__ __forceinline__ int lds_off(int p, int g) {
    return p * 128 + (((g) ^ (p & 7)) << 4);
}

// ---------------------------------------------------------------------------
// pack weights into MFMA B-frag order + BN affine fold (proven r1-r17)
__global__ void k_pack(const float* __restrict__ w1, const float* __restrict__ w2,
                       const float* __restrict__ b1, const float* __restrict__ g1,
                       const float* __restrict__ be1, const float* __restrict__ m1,
                       const float* __restrict__ v1,
                       const float* __restrict__ b2, const float* __restrict__ g2,
                       const float* __restrict__ be2, const float* __restrict__ m2,
                       const float* __restrict__ v2,
                       bf16* __restrict__ wp1, bf16* __restrict__ wp2,
                       float* __restrict__ aff)
{
    int idx = blockIdx.x * 256 + threadIdx.x;
    if (idx < 2 * 36864) {
        int conv = idx / 36864;
        int u = idx - conv * 36864;
        int j  = u & 7;
        int l  = (u >> 3) & 63;
        int nb = (u >> 9) & 3;
        int kb = (u >> 11) & 1;
        int t  = u >> 12;                  // 0..8
        int co = nb * 16 + (l & 15);
        int ci = kb * 32 + ((l >> 4) << 3) + j;
        const float* w = conv ? w2 : w1;
        float val = w[(co * 64 + ci) * 9 + t];
        (conv ? wp2 : wp1)[u] = (bf16)val;
    } else {
        int c = idx - 2 * 36864;
        if (c < 64) {
            float s = g1[c] / sqrtf(v1[c] + C_EPS);
            aff[c]      = s;
            aff[64 + c] = b1[c] * s + (be1[c] - m1[c] * s);
        } else if (c < 128) {
            int cc = c - 64;
            float s = g2[cc] / sqrtf(v2[cc] + C_EPS);
            aff[128 + cc] = s;
            aff[192 + cc] = b2[cc] * s + (be2[cc] - m2[cc] * s);
        }
    }
}

// ---------------------------------------------------------------------------
// Fully fused, 768 threads (12 waves), ONE block per CU.
// Why 768: h-accumulator floor = 20736 f32 / threads. 256thr -> 96 AGPR
// (total ~212 regs, pinned at 8 waves/CU, r7-r17). 768thr -> 32 AGPR
// (conv1 acc1[2][4], conv2 acc2[2][4]); est peak ~147 regs <= 170 cap of
// __launch_bounds__(768,3) with 23-reg margin (r14 spilled at ~6 margin).
// -> 12 waves/CU (+50%). LDS 64000 B (1 block) unchanged.
//   sx [0, 51200) : x 20x20 halo; then h 18x18 [0,41472); then acc [0,34304)
//   se [51200, 64000) : 10x10 half-res edge taps
// Phase bodies verbatim r17; only the wave->work partition changes
// (guarded-stride pattern proven at 6 waves in r12/r13).
__global__ __launch_bounds__(768, 3)
void k_fused(const float* __restrict__ x, const bf16* __restrict__ wp1,
             const bf16* __restrict__ wp2, const float* __restrict__ aff,
             const float* __restrict__ aprelu, float* __restrict__ out)
{
    __shared__ uint4 smem[4000];                 // 64000 B
    char* sx = reinterpret_cast<char*>(smem);
    char* se = reinterpret_cast<char*>(smem) + 51200;
    const int t = threadIdx.x;

    // XCD-bijective swizzle (2048 blocks, 8 XCDs): each XCD owns one image
    const int bid = blockIdx.x;
    const int logical = (bid & 7) * 256 + (bid >> 3);
    const int x0 = (logical & 15) * 16;
    const int y0 = ((logical >> 4) & 15) * 16;
    const int bb = logical >> 8;
    const float* xb = x + (size_t)bb * NC_ * HP_;

    // ---- phase 1: stage x 20x20 halo as PIXEL-PAIRS (float2 per plane).
    // 3200 items = 16 ci4 * 200 pairs; 5 guarded iters at 768 threads.
    for (int i = 0; i < 5; ++i) {
        int item = i * 768 + t;
        if (item < 3200) {
            int ci4 = item / 200;
            int pp  = item - ci4 * 200;          // pair 0..199
            int r   = pp / 10;
            int c2  = (pp - r * 10) * 2;         // 0,2,..,18
            int yy = y0 - 2 + r, xx = x0 - 2 + c2;
            float2 q0 = {0.f, 0.f}, q1 = {0.f, 0.f}, q2 = {0.f, 0.f}, q3 = {0.f, 0.f};
            if (yy >= 0 && yy < NH_ && xx >= 0 && xx < NW_) {
                const float* s = xb + (size_t)(ci4 * 4) * HP_ + yy * NW_ + xx;
                q0 = *reinterpret_cast<const float2*>(s);
                q1 = *reinterpret_cast<const float2*>(s + HP_);
                q2 = *reinterpret_cast<const float2*>(s + 2 * HP_);
                q3 = *reinterpret_cast<const float2*>(s + 3 * HP_);
            }
            int p = r * 20 + c2;
            int off = ((ci4 & 1) << 3);
            bf16x4 pkA = { (bf16)q0.x, (bf16)q1.x, (bf16)q2.x, (bf16)q3.x };
            bf16x4 pkB = { (bf16)q0.y, (bf16)q1.y, (bf16)q2.y, (bf16)q3.y };
            *reinterpret_cast<bf16x4*>(sx + lds_off(p,     ci4 >> 1) + off) = pkA;
            *reinterpret_cast<bf16x4*>(sx + lds_off(p + 1, ci4 >> 1) + off) = pkB;
        }
    }
    __syncthreads();

    const int w = t >> 6, l = t & 63;            // w in 0..11
    const int l15 = l & 15, lg = l >> 4;

    // ---- phase 2a: se taps, vectorized (r15-proven): 800 units, b128 ops.
    // Reads sx, writes se: disjoint regions, safe alongside conv1's reads.
    for (int i = 0; i < 2; ++i) {
        int u = i * 768 + t;
        if (u < 800) {
            int hp = u >> 3, g = u & 7;
            int ry = hp / 10, rx = hp - ry * 10;
            int ryg = (y0 >> 1) - 1 + ry; ryg = ryg < 0 ? 0 : (ryg > 127 ? 127 : ryg);
            int rxg = (x0 >> 1) - 1 + rx; rxg = rxg < 0 ? 0 : (rxg > 127 ? 127 : rxg);
            int pA = (2 * ryg - y0 + 2) * 20 + (2 * rxg - x0 + 2);
            bf16x8 a  = *reinterpret_cast<const bf16x8*>(sx + lds_off(pA,      g));
            bf16x8 b_ = *reinterpret_cast<const bf16x8*>(sx + lds_off(pA + 1,  g));
            bf16x8 c_ = *reinterpret_cast<const bf16x8*>(sx + lds_off(pA + 20, g));
            bf16x8 d_ = *reinterpret_cast<const bf16x8*>(sx + lds_off(pA + 21, g));
            bf16x8 e;
            #pragma unroll
            for (int j = 0; j < 8; ++j)
                e[j] = (bf16)((3.f * (float)a[j] - (float)b_[j] - (float)c_[j] - (float)d_[j]) * 0.5f);
            *reinterpret_cast<bf16x8*>(se + lds_off(hp, g)) = e;
        }
    }

    // ---- phase 2b: conv1 MFMAs -> 21 fragments over 12 waves, 2/wave max
    f32x4 acc1[2][4];
    #pragma unroll
    for (int j = 0; j < 2; ++j)
        #pragma unroll
        for (int cb = 0; cb < 4; ++cb) acc1[j][cb] = f32x4{0.f, 0.f, 0.f, 0.f};

    int prj[2], pcj[2];
    #pragma unroll
    for (int j = 0; j < 2; ++j) {
        int g = w + 12 * j;
        int p = g * 16 + l15; if (p > 323) p = 323;   // addr-safe clamp
        prj[j] = p / 18; pcj[j] = p - prj[j] * 18;
    }

    const bf16x8* wv1 = reinterpret_cast<const bf16x8*>(wp1);
    __builtin_amdgcn_s_setprio(1);
    #pragma unroll
    for (int ky = 0; ky < 3; ++ky)
    #pragma unroll
    for (int kx = 0; kx < 3; ++kx)
    #pragma unroll
    for (int kb = 0; kb < 2; ++kb) {
        const int tap = ky * 3 + kx;
        bf16x8 wf[4];
        #pragma unroll
        for (int cb = 0; cb < 4; ++cb)
            wf[cb] = wv1[(((tap * 2 + kb) * 4 + cb) << 6) + l];
        #pragma unroll
        for (int j = 0; j < 2; ++j) {
            if (w + 12 * j > 20) continue;       // wave-uniform guard
            bf16x8 xf = *reinterpret_cast<const bf16x8*>(
                sx + lds_off((prj[j] + ky) * 20 + pcj[j] + kx, kb * 4 + lg));
            #pragma unroll
            for (int cb = 0; cb < 4; ++cb)
                acc1[j][cb] = __builtin_amdgcn_mfma_f32_16x16x32_bf16(wf[cb], xf, acc1[j][cb], 0, 0, 0);
        }
    }
    __builtin_amdgcn_s_setprio(0);
    __syncthreads();                             // x reads + se writes complete

    // ---- phase 3: BN1 + PReLU, h over x px 0..323 (bytes [0,41472)).
    // h pixels whose GLOBAL coords fall outside the image must be ZERO
    // (conv2's SAME padding pads h with zeros) — not conv1-of-padded-x.
    {
        const float apv = aprelu[0];
        #pragma unroll
        for (int j = 0; j < 2; ++j) {
            int g = w + 12 * j;
            if (g > 20) continue;
            int p = g * 16 + l15;
            if (p < 324) {
                const int hy = y0 - 1 + prj[j];
                const int hx = x0 - 1 + pcj[j];
                const bool valid = (hy >= 0) && (hy < NH_) && (hx >= 0) && (hx < NW_);
                #pragma unroll
                for (int cb = 0; cb < 4; ++cb) {
                    f32x4 al = *reinterpret_cast<const f32x4*>(aff + cb * 16 + lg * 4);
                    f32x4 be = *reinterpret_cast<const f32x4*>(aff + 64 + cb * 16 + lg * 4);
                    bf16x4 pk;
                    #pragma unroll
                    for (int r = 0; r < 4; ++r) {
                        float zv = acc1[j][cb][r] * al[r] + be[r];
                        float hv = zv > 0.f ? zv : apv * zv;
                        pk[r] = valid ? (bf16)hv : (bf16)0.f;
                    }
                    *reinterpret_cast<bf16x4*>(sx + lds_off(p, cb * 2 + (lg >> 1)) + ((lg & 1) << 3)) = pk;
                }
            }
        }
    }
    __syncthreads();                             // h tile visible to all

    // ---- phase 4: conv2 MFMAs (M = pixels, N = co); 16 rows over 12 waves,
    // wave w does rows w and w+12 (guard <16) — row form proven in r12/r13.
    f32x4 acc2[2][4];
    #pragma unroll
    for (int a = 0; a < 2; ++a)
        #pragma unroll
        for (int b = 0; b < 4; ++b) acc2[a][b] = f32x4{0.f, 0.f, 0.f, 0.f};

    const bf16x8* wv2 = reinterpret_cast<const bf16x8*>(wp2);
    __builtin_amdgcn_s_setprio(1);
    #pragma unroll
    for (int ky = 0; ky < 3; ++ky)
    #pragma unroll
    for (int kx = 0; kx < 3; ++kx)
    #pragma unroll
    for (int kb = 0; kb < 2; ++kb) {
        const int tap = ky * 3 + kx;
        bf16x8 wf[4];
        #pragma unroll
        for (int cb = 0; cb < 4; ++cb)
            wf[cb] = wv2[(((tap * 2 + kb) * 4 + cb) << 6) + l];
        #pragma unroll
        for (int j = 0; j < 2; ++j) {
            const int row = w + 12 * j;
            if (row > 15) continue;              // wave-uniform guard
            int p = (row + ky) * 18 + (l15 + kx);
            bf16x8 xf = *reinterpret_cast<const bf16x8*>(sx + lds_off(p, kb * 4 + lg));
            #pragma unroll
            for (int cb = 0; cb < 4; ++cb)
                acc2[j][cb] = __builtin_amdgcn_mfma_f32_16x16x32_bf16(xf, wf[cb], acc2[j][cb], 0, 0, 0);
        }
    }
    __builtin_amdgcn_s_setprio(0);
    __syncthreads();                             // all h reads done -> h region dead

    // ---- phase 5a: stage acc2 as bf16 [co][yloc][X] over the dead h region.
    // co-stride ACC_STRIDE=536 B -> <=2-way bank aliasing (free, m136).
    #pragma unroll
    for (int j = 0; j < 2; ++j) {
        const int yloc = w + 12 * j;
        if (yloc > 15) continue;
        #pragma unroll
        for (int cb = 0; cb < 4; ++cb) {
            const int co = cb * 16 + l15;
            bf16x4 pk;
            #pragma unroll
            for (int r = 0; r < 4; ++r) pk[r] = (bf16)acc2[j][cb][r];
            *reinterpret_cast<bf16x4*>(sx + co * ACC_STRIDE + yloc * 32 + lg * 8) = pk;
        }
    }
    __syncthreads();

    // ---- phase 5b: readback. 4-lane groups own one (co, Y) row-quad ->
    // x-loads and out-stores are contiguous 64-B runs. 1024 (co,yloc) pairs
    // over 192 groups -> 6 guarded iters. Math verbatim r17.
    {
        const float* xb2 = x + (size_t)bb * NC_ * HP_;
        float* ob = out + (size_t)bb * NC_ * HP_;
        const int Xq = t & 3;
        #pragma unroll
        for (int iter = 0; iter < 6; ++iter) {
            const int pi = iter * 192 + (t >> 2);
            if (pi < 1024) {
                const int co = pi & 63;
                const int yloc = pi >> 6;
                bf16x4 av = *reinterpret_cast<const bf16x4*>(sx + co * ACC_STRIDE + yloc * 32 + Xq * 8);
                const float al = aff[128 + co];
                const float bt = aff[192 + co];
                const int t0 = (yloc + 1) >> 1;
                const float wyl = (yloc & 1) ? 0.75f : 0.25f;
                const int cib2 = co >> 3, cio = (co & 7) << 1;
                float etc[2][4];
                #pragma unroll
                for (int sr = 0; sr < 2; ++sr)
                    #pragma unroll
                    for (int cc = 0; cc < 4; ++cc) {
                        int ep = (t0 + sr) * 10 + 2 * Xq + cc;
                        etc[sr][cc] = (float)*reinterpret_cast<const bf16*>(se + lds_off(ep, cib2) + cio);
                    }
                const size_t goff = (size_t)co * HP_ + (y0 + yloc) * NW_ + x0 + Xq * 4;
                f32x4 xv = *reinterpret_cast<const f32x4*>(xb2 + goff);
                f32x4 o;
                #pragma unroll
                for (int rr = 0; rr < 4; ++rr) {
                    const int rx0 = (rr + 1) >> 1;        // {0,1,1,2}
                    const float wxl = (rr & 1) ? 0.75f : 0.25f;
                    float e0 = wxl * etc[0][rx0] + (1.f - wxl) * etc[0][rx0 + 1];
                    float e1 = wxl * etc[1][rx0] + (1.f - wxl) * etc[1][rx0 + 1];
                    float e  = wyl * e0 + (1.f - wyl) * e1;
                    o[rr] = (float)av[rr] * al + bt + xv[rr] + e;
                }
                *reinterpret_cast<f32x4*>(ob + goff) = o;
            }
        }
    }
}

// ---------------------------------------------------------------------------
extern "C" void kernel_launch(void* const* d_in, const int* in_sizes, int n_in,
                              void* d_out, int out_size, void* d_ws, size_t ws_size,
                              hipStream_t stream)
{
    const float* x   = (const float*)d_in[0];
    const float* w1  = (const float*)d_in[1];
    const float* b1  = (const float*)d_in[2];
    const float* g1  = (const float*)d_in[3];
    const float* be1 = (const float*)d_in[4];
    const float* m1  = (const float*)d_in[5];
    const float* v1  = (const float*)d_in[6];
    const float* ap  = (const float*)d_in[7];
    const float* w2  = (const float*)d_in[8];
    const float* b2  = (const float*)d_in[9];
    const float* g2  = (const float*)d_in[10];
    const float* be2 = (const float*)d_in[11];
    const float* m2  = (const float*)d_in[12];
    const float* v2  = (const float*)d_in[13];

    char* ws = (char*)d_ws;
    bf16*  wp1  = (bf16*)(ws + OFF_W1);
    bf16*  wp2  = (bf16*)(ws + OFF_W2);
    float* aff  = (float*)(ws + OFF_AFF);
    float* outp = (float*)d_out;

    k_pack<<<dim3(290), dim3(256), 0, stream>>>(w1, w2, b1, g1, be1, m1, v1,
                                                b2, g2, be2, m2, v2, wp1, wp2, aff);
    k_fused<<<dim3(2048), dim3(768), 0, stream>>>(x, wp1, wp2, aff, ap, outp);
}

// Round 19
// 164.410 us; speedup vs baseline: 1.2092x; 1.2092x over previous
//
#include <hip/hip_runtime.h>
#include <cstdint>
#include <cstddef>

typedef __bf16 bf16;
typedef __bf16 bf16x8 __attribute__((ext_vector_type(8)));
typedef __bf16 bf16x4 __attribute__((ext_vector_type(4)));
typedef float  f32x4  __attribute__((ext_vector_type(4)));

#define C_EPS 1e-5f
#define NC_ 64
#define NH_ 256
#define NW_ 256
#define HP_ (NH_*NW_)

// workspace layout (bytes)
#define OFF_W1   0ull
#define OFF_W2   73728ull
#define OFF_AFF  147456ull

// acc staging stride (phase 5): 536 B -> 134 ≡ 6 (mod 32) banks, <=2-way.
#define ACC_STRIDE 536

// swizzled LDS byte offset for [pixel p][granule g] bf16 tile (128 B/pixel),
// 16-B-granule XOR swizzle: pixel stride 128 B == 32 banks -> must swizzle.
// granule g holds ci 8g..8g+7 (staging stores ci4 at g=ci4>>1, +8B if odd).
__device__ __forceinline__ int lds_off(int p, int g) {
    return p * 128 + (((g) ^ (p & 7)) << 4);
}

// ---------------------------------------------------------------------------
// pack weights into MFMA B-frag order + BN affine fold (proven r1-r17)
__global__ void k_pack(const float* __restrict__ w1, const float* __restrict__ w2,
                       const float* __restrict__ b1, const float* __restrict__ g1,
                       const float* __restrict__ be1, const float* __restrict__ m1,
                       const float* __restrict__ v1,
                       const float* __restrict__ b2, const float* __restrict__ g2,
                       const float* __restrict__ be2, const float* __restrict__ m2,
                       const float* __restrict__ v2,
                       bf16* __restrict__ wp1, bf16* __restrict__ wp2,
                       float* __restrict__ aff)
{
    int idx = blockIdx.x * 256 + threadIdx.x;
    if (idx < 2 * 36864) {
        int conv = idx / 36864;
        int u = idx - conv * 36864;
        int j  = u & 7;
        int l  = (u >> 3) & 63;
        int nb = (u >> 9) & 3;
        int kb = (u >> 11) & 1;
        int t  = u >> 12;                  // 0..8
        int co = nb * 16 + (l & 15);
        int ci = kb * 32 + ((l >> 4) << 3) + j;
        const float* w = conv ? w2 : w1;
        float val = w[(co * 64 + ci) * 9 + t];
        (conv ? wp2 : wp1)[u] = (bf16)val;
    } else {
        int c = idx - 2 * 36864;
        if (c < 64) {
            float s = g1[c] / sqrtf(v1[c] + C_EPS);
            aff[c]      = s;
            aff[64 + c] = b1[c] * s + (be1[c] - m1[c] * s);
        } else if (c < 128) {
            int cc = c - 64;
            float s = g2[cc] / sqrtf(v2[cc] + C_EPS);
            aff[128 + cc] = s;
            aff[192 + cc] = b2[cc] * s + (be2[cc] - m2[cc] * s);
        }
    }
}

// ---------------------------------------------------------------------------
// Fully fused (r17 structure; se phase moved AFTER conv1 MFMAs so MFMA issue
// starts immediately and se LDS/VALU runs in the MFMA shadow):
//   sx [0, 51200) : x 20x20 halo; then h 18x18 [0,41472); then acc [0,34304)
//   se [51200, 64000) : 10x10 half-res edge taps
// stage x (float2 pairs) -> bar -> [conv1 MFMA, then se vectorized] -> bar
// -> h over x (zero outside image = conv2 SAME padding) -> bar -> conv2 MFMA
// -> bar -> acc2 bf16 [co][yloc][X] over dead h region -> bar -> readback:
// 4-lane groups own (co,Y) rows -> BN2 + x + bilinear(se), coalesced f32x4.
// Keep __launch_bounds__(256,2): every tighter cap spills or starves ILP
// (r6/r11/r12/r14/r18); 2 blocks/CU gives the phase-overlap that 1 block
// of 12 waves lacks (r18: 34% occupancy but slower).
__global__ __launch_bounds__(256, 2)
void k_fused(const float* __restrict__ x, const bf16* __restrict__ wp1,
             const bf16* __restrict__ wp2, const float* __restrict__ aff,
             const float* __restrict__ aprelu, float* __restrict__ out)
{
    __shared__ uint4 smem[4000];                 // 64000 B
    char* sx = reinterpret_cast<char*>(smem);
    char* se = reinterpret_cast<char*>(smem) + 51200;
    const int t = threadIdx.x;

    // XCD-bijective swizzle (2048 blocks, 8 XCDs): each XCD owns one image
    const int bid = blockIdx.x;
    const int logical = (bid & 7) * 256 + (bid >> 3);
    const int x0 = (logical & 15) * 16;
    const int y0 = ((logical >> 4) & 15) * 16;
    const int bb = logical >> 8;
    const float* xb = x + (size_t)bb * NC_ * HP_;

    // ---- phase 1: stage x 20x20 halo as PIXEL-PAIRS (float2 per plane).
    // xx is even and NW=256 -> a pair is all-in or all-out at boundaries.
    for (int i = 0; i < 13; ++i) {
        int item = i * 256 + t;
        if (item < 3200) {
            int ci4 = item / 200;
            int pp  = item - ci4 * 200;          // pair 0..199
            int r   = pp / 10;
            int c2  = (pp - r * 10) * 2;         // 0,2,..,18
            int yy = y0 - 2 + r, xx = x0 - 2 + c2;
            float2 q0 = {0.f, 0.f}, q1 = {0.f, 0.f}, q2 = {0.f, 0.f}, q3 = {0.f, 0.f};
            if (yy >= 0 && yy < NH_ && xx >= 0 && xx < NW_) {
                const float* s = xb + (size_t)(ci4 * 4) * HP_ + yy * NW_ + xx;
                q0 = *reinterpret_cast<const float2*>(s);
                q1 = *reinterpret_cast<const float2*>(s + HP_);
                q2 = *reinterpret_cast<const float2*>(s + 2 * HP_);
                q3 = *reinterpret_cast<const float2*>(s + 3 * HP_);
            }
            int p = r * 20 + c2;
            int off = ((ci4 & 1) << 3);
            bf16x4 pkA = { (bf16)q0.x, (bf16)q1.x, (bf16)q2.x, (bf16)q3.x };
            bf16x4 pkB = { (bf16)q0.y, (bf16)q1.y, (bf16)q2.y, (bf16)q3.y };
            *reinterpret_cast<bf16x4*>(sx + lds_off(p,     ci4 >> 1) + off) = pkA;
            *reinterpret_cast<bf16x4*>(sx + lds_off(p + 1, ci4 >> 1) + off) = pkB;
        }
    }
    __syncthreads();

    const int w = t >> 6, l = t & 63;
    const int l15 = l & 15, lg = l >> 4;

    // ---- phase 2a: conv1 MFMAs -> 18x18 h in registers (r10 verbatim).
    // Issued FIRST in the epoch so the matrix pipe starts immediately.
    f32x4 acc1[6][4];
    #pragma unroll
    for (int j = 0; j < 6; ++j)
        #pragma unroll
        for (int cb = 0; cb < 4; ++cb) acc1[j][cb] = f32x4{0.f, 0.f, 0.f, 0.f};

    int prj[6], pcj[6];
    #pragma unroll
    for (int j = 0; j < 6; ++j) {
        int g = w + 4 * j;
        int p = g * 16 + l15; if (p > 323) p = 323;   // addr-safe clamp
        prj[j] = p / 18; pcj[j] = p - prj[j] * 18;
    }

    const bf16x8* wv1 = reinterpret_cast<const bf16x8*>(wp1);
    __builtin_amdgcn_s_setprio(1);
    #pragma unroll
    for (int ky = 0; ky < 3; ++ky)
    #pragma unroll
    for (int kx = 0; kx < 3; ++kx)
    #pragma unroll
    for (int kb = 0; kb < 2; ++kb) {
        const int tap = ky * 3 + kx;
        bf16x8 wf[4];
        #pragma unroll
        for (int cb = 0; cb < 4; ++cb)
            wf[cb] = wv1[(((tap * 2 + kb) * 4 + cb) << 6) + l];
        #pragma unroll
        for (int j = 0; j < 6; ++j) {
            if (w + 4 * j > 20) continue;        // wave-uniform guard
            bf16x8 xf = *reinterpret_cast<const bf16x8*>(
                sx + lds_off((prj[j] + ky) * 20 + pcj[j] + kx, kb * 4 + lg));
            #pragma unroll
            for (int cb = 0; cb < 4; ++cb)
                acc1[j][cb] = __builtin_amdgcn_mfma_f32_16x16x32_bf16(wf[cb], xf, acc1[j][cb], 0, 0, 0);
        }
    }
    __builtin_amdgcn_s_setprio(0);

    // ---- phase 2b: se taps, vectorized (r15-proven), now in the MFMA
    // shadow: 800 units, b128 ops. Reads sx, writes se (disjoint regions —
    // same barrier-epoch hazard argument as r15/r16/r17).
    for (int i = 0; i < 4; ++i) {
        int u = i * 256 + t;
        if (u < 800) {
            int hp = u >> 3, g = u & 7;
            int ry = hp / 10, rx = hp - ry * 10;
            int ryg = (y0 >> 1) - 1 + ry; ryg = ryg < 0 ? 0 : (ryg > 127 ? 127 : ryg);
            int rxg = (x0 >> 1) - 1 + rx; rxg = rxg < 0 ? 0 : (rxg > 127 ? 127 : rxg);
            int pA = (2 * ryg - y0 + 2) * 20 + (2 * rxg - x0 + 2);
            bf16x8 a  = *reinterpret_cast<const bf16x8*>(sx + lds_off(pA,      g));
            bf16x8 b_ = *reinterpret_cast<const bf16x8*>(sx + lds_off(pA + 1,  g));
            bf16x8 c_ = *reinterpret_cast<const bf16x8*>(sx + lds_off(pA + 20, g));
            bf16x8 d_ = *reinterpret_cast<const bf16x8*>(sx + lds_off(pA + 21, g));
            bf16x8 e;
            #pragma unroll
            for (int j = 0; j < 8; ++j)
                e[j] = (bf16)((3.f * (float)a[j] - (float)b_[j] - (float)c_[j] - (float)d_[j]) * 0.5f);
            *reinterpret_cast<bf16x8*>(se + lds_off(hp, g)) = e;
        }
    }
    __syncthreads();                             // x reads + se writes complete

    // ---- phase 3: BN1 + PReLU, h over x px 0..323 (bytes [0,41472)).
    // h pixels whose GLOBAL coords fall outside the image must be ZERO
    // (conv2's SAME padding pads h with zeros) — not conv1-of-padded-x.
    {
        const float apv = aprelu[0];
        #pragma unroll
        for (int j = 0; j < 6; ++j) {
            int g = w + 4 * j;
            if (g > 20) continue;
            int p = g * 16 + l15;
            if (p < 324) {
                const int hy = y0 - 1 + prj[j];
                const int hx = x0 - 1 + pcj[j];
                const bool valid = (hy >= 0) && (hy < NH_) && (hx >= 0) && (hx < NW_);
                #pragma unroll
                for (int cb = 0; cb < 4; ++cb) {
                    f32x4 al = *reinterpret_cast<const f32x4*>(aff + cb * 16 + lg * 4);
                    f32x4 be = *reinterpret_cast<const f32x4*>(aff + 64 + cb * 16 + lg * 4);
                    bf16x4 pk;
                    #pragma unroll
                    for (int r = 0; r < 4; ++r) {
                        float zv = acc1[j][cb][r] * al[r] + be[r];
                        float hv = zv > 0.f ? zv : apv * zv;
                        pk[r] = valid ? (bf16)hv : (bf16)0.f;
                    }
                    *reinterpret_cast<bf16x4*>(sx + lds_off(p, cb * 2 + (lg >> 1)) + ((lg & 1) << 3)) = pk;
                }
            }
        }
    }
    __syncthreads();                             // h tile visible to all

    // ---- phase 4: conv2 MFMAs (M = pixels, N = co) (r10 verbatim)
    f32x4 acc2[4][4];
    #pragma unroll
    for (int a = 0; a < 4; ++a)
        #pragma unroll
        for (int b = 0; b < 4; ++b) acc2[a][b] = f32x4{0.f, 0.f, 0.f, 0.f};

    const bf16x8* wv2 = reinterpret_cast<const bf16x8*>(wp2);
    __builtin_amdgcn_s_setprio(1);
    #pragma unroll
    for (int ky = 0; ky < 3; ++ky)
    #pragma unroll
    for (int kx = 0; kx < 3; ++kx)
    #pragma unroll
    for (int kb = 0; kb < 2; ++kb) {
        const int tap = ky * 3 + kx;
        bf16x8 wf[4];
        #pragma unroll
        for (int cb = 0; cb < 4; ++cb)
            wf[cb] = wv2[(((tap * 2 + kb) * 4 + cb) << 6) + l];
        #pragma unroll
        for (int pr = 0; pr < 4; ++pr) {
            int p = (w * 4 + pr + ky) * 18 + (l15 + kx);
            bf16x8 xf = *reinterpret_cast<const bf16x8*>(sx + lds_off(p, kb * 4 + lg));
            #pragma unroll
            for (int cb = 0; cb < 4; ++cb)
                acc2[pr][cb] = __builtin_amdgcn_mfma_f32_16x16x32_bf16(xf, wf[cb], acc2[pr][cb], 0, 0, 0);
        }
    }
    __builtin_amdgcn_s_setprio(0);
    __syncthreads();                             // all h reads done -> h region dead

    // ---- phase 5a: stage acc2 as bf16 [co][yloc][X] over the dead h region.
    // co-stride ACC_STRIDE=536 B -> <=2-way bank aliasing (free, m136).
    #pragma unroll
    for (int pr = 0; pr < 4; ++pr) {
        const int yloc = w * 4 + pr;
        #pragma unroll
        for (int cb = 0; cb < 4; ++cb) {
            const int co = cb * 16 + l15;
            bf16x4 pk;
            #pragma unroll
            for (int r = 0; r < 4; ++r) pk[r] = (bf16)acc2[pr][cb][r];
            *reinterpret_cast<bf16x4*>(sx + co * ACC_STRIDE + yloc * 32 + lg * 8) = pk;
        }
    }
    __syncthreads();

    // ---- phase 5b: readback. 4-lane groups own one (co, Y) row-quad ->
    // x-loads and out-stores are contiguous 64-B runs (16 tx/instr vs 64).
    // Same per-element math as r15 (row/col parity identities, r12-proven).
    {
        const float* xb2 = x + (size_t)bb * NC_ * HP_;
        float* ob = out + (size_t)bb * NC_ * HP_;
        const int Xq = t & 3;
        #pragma unroll
        for (int iter = 0; iter < 16; ++iter) {
            const int pi = iter * 64 + (t >> 2);
            const int co = pi & 63;
            const int yloc = pi >> 6;
            bf16x4 av = *reinterpret_cast<const bf16x4*>(sx + co * ACC_STRIDE + yloc * 32 + Xq * 8);
            const float al = aff[128 + co];
            const float bt = aff[192 + co];
            const int t0 = (yloc + 1) >> 1;
            const float wyl = (yloc & 1) ? 0.75f : 0.25f;
            const int cib2 = co >> 3, cio = (co & 7) << 1;
            float etc[2][4];
            #pragma unroll
            for (int sr = 0; sr < 2; ++sr)
                #pragma unroll
                for (int cc = 0; cc < 4; ++cc) {
                    int ep = (t0 + sr) * 10 + 2 * Xq + cc;
                    etc[sr][cc] = (float)*reinterpret_cast<const bf16*>(se + lds_off(ep, cib2) + cio);
                }
            const size_t goff = (size_t)co * HP_ + (y0 + yloc) * NW_ + x0 + Xq * 4;
            f32x4 xv = *reinterpret_cast<const f32x4*>(xb2 + goff);
            f32x4 o;
            #pragma unroll
            for (int rr = 0; rr < 4; ++rr) {
                const int rx0 = (rr + 1) >> 1;            // {0,1,1,2}
                const float wxl = (rr & 1) ? 0.75f : 0.25f;
                float e0 = wxl * etc[0][rx0] + (1.f - wxl) * etc[0][rx0 + 1];
                float e1 = wxl * etc[1][rx0] + (1.f - wxl) * etc[1][rx0 + 1];
                float e  = wyl * e0 + (1.f - wyl) * e1;
                o[rr] = (float)av[rr] * al + bt + xv[rr] + e;
            }
            *reinterpret_cast<f32x4*>(ob + goff) = o;
        }
    }
}

// ---------------------------------------------------------------------------
extern "C" void kernel_launch(void* const* d_in, const int* in_sizes, int n_in,
                              void* d_out, int out_size, void* d_ws, size_t ws_size,
                              hipStream_t stream)
{
    const float* x   = (const float*)d_in[0];
    const float* w1  = (const float*)d_in[1];
    const float* b1  = (const float*)d_in[2];
    const float* g1  = (const float*)d_in[3];
    const float* be1 = (const float*)d_in[4];
    const float* m1  = (const float*)d_in[5];
    const float* v1  = (const float*)d_in[6];
    const float* ap  = (const float*)d_in[7];
    const float* w2  = (const float*)d_in[8];
    const float* b2  = (const float*)d_in[9];
    const float* g2  = (const float*)d_in[10];
    const float* be2 = (const float*)d_in[11];
    const float* m2  = (const float*)d_in[12];
    const float* v2  = (const float*)d_in[13];

    char* ws = (char*)d_ws;
    bf16*  wp1  = (bf16*)(ws + OFF_W1);
    bf16*  wp2  = (bf16*)(ws + OFF_W2);
    float* aff  = (float*)(ws + OFF_AFF);
    float* outp = (float*)d_out;

    k_pack<<<dim3(290), dim3(256), 0, stream>>>(w1, w2, b1, g1, be1, m1, v1,
                                                b2, g2, be2, m2, v2, wp1, wp2, aff);
    k_fused<<<dim3(2048), dim3(256), 0, stream>>>(x, wp1, wp2, aff, ap, outp);
}